// Round 1
// baseline (2882.291 us; speedup 1.0000x reference)
//
#include <hip/hip_runtime.h>
#include <math.h>

#define RR 3
#define NN 300000
#define HH 256
#define GG 2048

// ---------------- block reduce helpers ----------------
__device__ __forceinline__ float block_reduce_sum(float v, float* rbuf) {
  const int tid = threadIdx.x;
  rbuf[tid] = v;
  __syncthreads();
  #pragma unroll
  for (int off = 128; off > 0; off >>= 1) {
    if (tid < off) rbuf[tid] = rbuf[tid] + rbuf[tid + off];
    __syncthreads();
  }
  const float r = rbuf[0];
  __syncthreads();
  return r;
}

__device__ __forceinline__ float block_reduce_max(float v, float* rbuf) {
  const int tid = threadIdx.x;
  rbuf[tid] = v;
  __syncthreads();
  #pragma unroll
  for (int off = 128; off > 0; off >>= 1) {
    if (tid < off) rbuf[tid] = fmaxf(rbuf[tid], rbuf[tid + off]);
    __syncthreads();
  }
  const float r = rbuf[0];
  __syncthreads();
  return r;
}

// ---------------- graph boundary kernel ----------------
// batch is sorted per rank; starts[r][g] = lower_bound(batch[r], g), g in [0,G]
__global__ void bounds_kernel(const int* __restrict__ batch, int* __restrict__ starts) {
  const int t = blockIdx.x * blockDim.x + threadIdx.x;
  if (t >= RR * (GG + 1)) return;
  const int r = t / (GG + 1);
  const int g = t - r * (GG + 1);
  const int* __restrict__ br = batch + (size_t)r * NN;
  int lo = 0, hi = NN;
  while (lo < hi) {
    const int mid = (lo + hi) >> 1;
    if (br[mid] < g) lo = mid + 1; else hi = mid;
  }
  starts[t] = lo;
}

// ---------------- score kernel: s = tanh(h@W1+b1)@w2 + b2 ----------------
// block tile: 64 nodes x 256 j, K tiled by 32 through LDS.
// thread tile: 8 nodes x 8 j (j strided by 32 -> conflict-free LDS reads)
constexpr int NT = 64;
constexpr int KT = 32;
constexpr int HPAD = 68;   // 64 nodes + pad, keeps float4 LDS reads 16B-aligned

__global__ __launch_bounds__(256) void score_kernel(
    const float* __restrict__ h, const float* __restrict__ W1,
    const float* __restrict__ b1, const float* __restrict__ w2,
    const float* __restrict__ b2, float* __restrict__ s_out)
{
  const int r = blockIdx.y;
  const int n0 = blockIdx.x * NT;
  const int tid = threadIdx.x;
  const int jg = tid & 31;   // thread's j = jg + 32*j, j=0..7
  const int ng = tid >> 5;   // thread's nodes = ng*8 + i, i=0..7

  const float* __restrict__ hr  = h  + (size_t)r * NN * HH;
  const float* __restrict__ W1r = W1 + (size_t)r * HH * HH;

  __shared__ float h_lds[KT][HPAD];     // [k][node]
  __shared__ float w_lds[KT][HH];       // [k][j]   32KB
  __shared__ float red[32][NT + 1];     // jg-group partial scores

  float acc[8][8];
  #pragma unroll
  for (int i = 0; i < 8; ++i)
    #pragma unroll
    for (int j = 0; j < 8; ++j) acc[i][j] = 0.f;

  for (int k0 = 0; k0 < HH; k0 += KT) {
    // stage h tile (64 nodes x 32 k), transposed into [k][node]
    #pragma unroll
    for (int rep = 0; rep < 2; ++rep) {
      const int id = tid + 256 * rep;       // 512 float4s
      const int nn = id >> 3;               // 0..63
      const int kq = (id & 7) << 2;         // 0,4,...,28
      const int gn = n0 + nn;
      float4 v = make_float4(0.f, 0.f, 0.f, 0.f);
      if (gn < NN) v = *(const float4*)(hr + (size_t)gn * HH + k0 + kq);
      h_lds[kq + 0][nn] = v.x;
      h_lds[kq + 1][nn] = v.y;
      h_lds[kq + 2][nn] = v.z;
      h_lds[kq + 3][nn] = v.w;
    }
    // stage W1 tile (32 k x 256 j), row-major copy, fully coalesced
    #pragma unroll
    for (int rep = 0; rep < 8; ++rep) {
      const int id = tid + 256 * rep;       // 2048 float4s
      const int row = id >> 6;              // 0..31
      const int col = (id & 63) << 2;       // 0..252
      *(float4*)(&w_lds[row][col]) = *(const float4*)(W1r + (size_t)(k0 + row) * HH + col);
    }
    __syncthreads();

    #pragma unroll 2
    for (int k = 0; k < KT; ++k) {
      const float4 ha = *(const float4*)(&h_lds[k][ng * 8]);
      const float4 hb = *(const float4*)(&h_lds[k][ng * 8 + 4]);
      const float hreg[8] = {ha.x, ha.y, ha.z, ha.w, hb.x, hb.y, hb.z, hb.w};
      float wreg[8];
      #pragma unroll
      for (int j = 0; j < 8; ++j) wreg[j] = w_lds[k][jg + 32 * j];
      #pragma unroll
      for (int i = 0; i < 8; ++i)
        #pragma unroll
        for (int j = 0; j < 8; ++j)
          acc[i][j] = fmaf(hreg[i], wreg[j], acc[i][j]);
    }
    __syncthreads();
  }

  // epilogue: tanh, dot with w2, reduce across the 32 j-groups
  float part[8];
  #pragma unroll
  for (int i = 0; i < 8; ++i) part[i] = 0.f;
  #pragma unroll
  for (int j = 0; j < 8; ++j) {
    const int jj = jg + 32 * j;
    const float bb = b1[r * HH + jj];
    const float ww = w2[r * HH + jj];
    #pragma unroll
    for (int i = 0; i < 8; ++i)
      part[i] += tanhf(acc[i][j] + bb) * ww;
  }
  #pragma unroll
  for (int i = 0; i < 8; ++i) red[jg][ng * 8 + i] = part[i];
  __syncthreads();
  if (tid < NT) {
    float ssum = 0.f;
    #pragma unroll
    for (int q = 0; q < 32; ++q) ssum += red[q][tid];
    const int gn = n0 + tid;
    if (gn < NN) s_out[(size_t)r * NN + gn] = ssum + b2[r];   // TAU = 1.0
  }
}

// ---------------- pooling + fused rank_proj ----------------
// one 256-thread block handles GPB graphs of one rank; thread = hidden dim
constexpr int GPB = 4;

__global__ __launch_bounds__(256) void pool_kernel(
    const float* __restrict__ h, const int* __restrict__ starts,
    const float* __restrict__ s, const float* __restrict__ Wp,
    const float* __restrict__ bp, float* __restrict__ state)
{
  const int r = blockIdx.y;
  const int tid = threadIdx.x;
  __shared__ float agg[GPB][4 * HH];   // [sm, mean, mx, att] rows, 16KB
  __shared__ float rbuf[256];
  const float* __restrict__ hr = h + (size_t)r * NN * HH;
  const float* __restrict__ sr = s + (size_t)r * NN;
  const int* __restrict__ str = starts + r * (GG + 1);

  for (int gg = 0; gg < GPB; ++gg) {
    const int g = blockIdx.x * GPB + gg;
    const int a = str[g];
    const int bnd = str[g + 1];
    const int cnt = bnd - a;

    // softmax max
    float lm = -3.402823466e38f;
    for (int i = a + tid; i < bnd; i += 256) lm = fmaxf(lm, sr[i]);
    const float m = block_reduce_max(lm, rbuf);

    // softmax denom
    float le = 0.f;
    for (int i = a + tid; i < bnd; i += 256) le += expf(sr[i] - m);
    const float denom = block_reduce_sum(le, rbuf);

    // fused h pass: att / sum / max pools; thread tid owns hidden dim tid
    float att = 0.f, smv = 0.f, mxv = -3.402823466e38f;
    #pragma unroll 2
    for (int n = a; n < bnd; ++n) {
      const float e = expf(sr[n] - m);                 // broadcast, cheap
      const float hv = hr[(size_t)n * HH + tid];       // coalesced 1KB/row
      att += e * hv;
      smv += hv;
      mxv = fmaxf(mxv, hv);
    }
    const float meanv = smv / fmaxf((float)cnt, 1.f);
    if (cnt == 0) { mxv = 0.f; att = 0.f; } else { att /= denom; }
    agg[gg][tid]          = smv;
    agg[gg][HH + tid]     = meanv;
    agg[gg][2 * HH + tid] = mxv;
    agg[gg][3 * HH + tid] = att;
  }
  __syncthreads();

  // fused rank_proj: state[g][r*H + j] = agg @ Wp + bp, 4-graph register block
  const float* __restrict__ Wpr = Wp + (size_t)r * 4 * HH * HH;
  float o[GPB];
  #pragma unroll
  for (int gg = 0; gg < GPB; ++gg) o[gg] = bp[r * HH + tid];
  for (int i = 0; i < 4 * HH; ++i) {
    const float w = Wpr[(size_t)i * HH + tid];         // coalesced
    #pragma unroll
    for (int gg = 0; gg < GPB; ++gg) o[gg] = fmaf(agg[gg][i], w, o[gg]);
  }
  #pragma unroll
  for (int gg = 0; gg < GPB; ++gg) {
    const int g = blockIdx.x * GPB + gg;
    state[(size_t)g * (RR * HH) + r * HH + tid] = o[gg];
  }
}

// ---------------- final MLP: LN -> SiLU -> Wf1 -> SiLU -> Wf2 ----------------
__global__ __launch_bounds__(256) void final_kernel(
    const float* __restrict__ state, const float* __restrict__ ln_g,
    const float* __restrict__ ln_b, const float* __restrict__ Wf1,
    const float* __restrict__ bf1, const float* __restrict__ Wf2,
    const float* __restrict__ bf2, float* __restrict__ out)
{
  const int g = blockIdx.x;
  const int tid = threadIdx.x;
  __shared__ float x_lds[RR * HH];
  __shared__ float rbuf[256];
  const float* __restrict__ st = state + (size_t)g * (RR * HH);

  float v[3];
  float lsum = 0.f, lsq = 0.f;
  #pragma unroll
  for (int p = 0; p < 3; ++p) {
    v[p] = st[tid + 256 * p];
    lsum += v[p];
    lsq += v[p] * v[p];
  }
  const float S = block_reduce_sum(lsum, rbuf);
  const float Q = block_reduce_sum(lsq, rbuf);
  const float mu = S * (1.f / 768.f);
  const float var = Q * (1.f / 768.f) - mu * mu;   // jnp.var (ddof=0)
  const float rstd = rsqrtf(var + 1e-5f);
  #pragma unroll
  for (int p = 0; p < 3; ++p) {
    const int idx = tid + 256 * p;
    float x = (v[p] - mu) * rstd * ln_g[idx] + ln_b[idx];
    x = x / (1.f + expf(-x));                      // SiLU
    x_lds[idx] = x;
  }
  __syncthreads();

  float acc = bf1[tid];
  #pragma unroll 4
  for (int i = 0; i < RR * HH; ++i)
    acc = fmaf(x_lds[i], Wf1[(size_t)i * HH + tid], acc);   // coalesced Wf1
  const float y = acc / (1.f + expf(-acc));                  // SiLU
  const float T = block_reduce_sum(y * Wf2[tid], rbuf);
  if (tid == 0) out[g] = T + bf2[0];
}

// ---------------- launch ----------------
extern "C" void kernel_launch(void* const* d_in, const int* in_sizes, int n_in,
                              void* d_out, int out_size, void* d_ws, size_t ws_size,
                              hipStream_t stream)
{
  const float* h    = (const float*)d_in[0];
  const int*   batch= (const int*)  d_in[1];
  const float* W1   = (const float*)d_in[2];
  const float* b1   = (const float*)d_in[3];
  const float* w2   = (const float*)d_in[4];
  const float* b2   = (const float*)d_in[5];
  const float* Wp   = (const float*)d_in[6];
  const float* bp   = (const float*)d_in[7];
  const float* ln_g = (const float*)d_in[8];
  const float* ln_b = (const float*)d_in[9];
  const float* Wf1  = (const float*)d_in[10];
  const float* bf1  = (const float*)d_in[11];
  const float* Wf2  = (const float*)d_in[12];
  const float* bf2  = (const float*)d_in[13];
  float* out = (float*)d_out;

  // workspace layout (all regions fully written before read):
  //   s:      R*N floats      = 3,600,000 B at offset 0
  //   starts: R*(G+1) ints    at offset 3,600,000 (32KB reserved)
  //   state:  G*R*H floats    = 6,291,456 B at offset 3,632,768
  char* ws = (char*)d_ws;
  float* s_buf = (float*)ws;
  int*   starts = (int*)(ws + (size_t)RR * NN * sizeof(float));
  float* state  = (float*)(ws + (size_t)RR * NN * sizeof(float) + 32768);

  bounds_kernel<<<(RR * (GG + 1) + 255) / 256, 256, 0, stream>>>(batch, starts);

  dim3 gs((NN + NT - 1) / NT, RR);
  score_kernel<<<gs, 256, 0, stream>>>(h, W1, b1, w2, b2, s_buf);

  dim3 gp(GG / GPB, RR);
  pool_kernel<<<gp, 256, 0, stream>>>(h, starts, s_buf, Wp, bp, state);

  final_kernel<<<GG, 256, 0, stream>>>(state, ln_g, ln_b, Wf1, bf1, Wf2, bf2, out);

  (void)in_sizes; (void)n_in; (void)out_size; (void)ws_size;
}